// Round 10
// baseline (142.643 us; speedup 1.0000x reference)
//
#include <hip/hip_runtime.h>
#include <hip/hip_bf16.h>
#include <hip/hip_fp8.h>

// SimCLR NT-Xent loss on MI355X.
// loss = -(1/2B) sum_t [ 10*G[t,j0(t)] - (10 + log sum_{j!=t} exp(10*G[t,j]-10)) ]
// where G = M M^T, M = l2norm rows of [z_i; z_j], j0 = (t%B==0) ? 1 : 0.
// Round 10: revert to round-5's proven fp8 16x16x32 compute path (MX 16x16x128
// abandoned: rounds 6-9 all lost to register pressure -- spills/conflicts).
// New: double-buffered K-pipeline in the SAME 32 KB LDS (KB=64, 4 x 8 KB):
// per chunk do ds_reads first, then issue next chunk's global_load_lds into
// the other buffer, then MFMA, then barrier -- prefetch latency overlapped
// by own-wave compute instead of stalling the vmcnt(0) drain.

#define BB 4096      // batch B
#define DD 512       // feature dim (bytes per row in fp8)
#define NN 8192      // 2B rows of G
#define TILE 128     // block tile (rows x cols)
#define KB 64        // K bytes staged per LDS chunk (8 chunks)
#define NBLK 2080    // 64*65/2 upper-triangle block tiles

typedef __attribute__((ext_vector_type(4))) float f32x4;

#define AS1 __attribute__((address_space(1)))
#define AS3 __attribute__((address_space(3)))
static __device__ __forceinline__ void gload_lds16(const void* g, void* l) {
    __builtin_amdgcn_global_load_lds((const AS1 void*)g, (AS3 void*)l, 16, 0, 0);
}

// ---------------- kernel 1: L2-normalize rows, cast to fp8; zero rowsum ----
// One wave per row: 64 lanes x 8 f32, shuffle reduce, no LDS/barrier.
__global__ __launch_bounds__(256)
void normalize_kernel(const float* __restrict__ zi, const float* __restrict__ zj,
                      unsigned char* __restrict__ M, float* __restrict__ rowsum) {
    const int wave = threadIdx.x >> 6;
    const int lane = threadIdx.x & 63;
    const int row  = blockIdx.x * 4 + wave;      // 2048 blocks * 4 rows
    if (threadIdx.x < 4) rowsum[blockIdx.x * 4 + threadIdx.x] = 0.f;
    const float* src = (row < BB) ? (zi + (size_t)row * DD)
                                  : (zj + (size_t)(row - BB) * DD);
    float4 v0 = ((const float4*)src)[lane * 2 + 0];
    float4 v1 = ((const float4*)src)[lane * 2 + 1];
    float ss = v0.x*v0.x + v0.y*v0.y + v0.z*v0.z + v0.w*v0.w
             + v1.x*v1.x + v1.y*v1.y + v1.z*v1.z + v1.w*v1.w;
    #pragma unroll
    for (int off = 1; off <= 32; off <<= 1) ss += __shfl_xor(ss, off);
    const float inv = rsqrtf(ss);
    const float vals[8] = {v0.x*inv, v0.y*inv, v0.z*inv, v0.w*inv,
                           v1.x*inv, v1.y*inv, v1.z*inv, v1.w*inv};
    union { long u; unsigned char b[8]; } pk;
    #pragma unroll
    for (int j = 0; j < 8; ++j)
        pk.b[j] = __hip_cvt_float_to_fp8(vals[j], __HIP_SATFINITE, __HIP_E4M3);
    ((long*)(M + (size_t)row * DD))[lane] = pk.u;
}

// ---------------- kernel 2: Gram tile + exp row/col sums -------------------
// 2080 blocks, one upper-triangle 128x128 tile each (by >= bx).
// Wave w: rows wr=(w>>1)*64, cols wc=(w&1)*64; 4x4 of 16x16x32 fp8 MFMA.
// LDS per buffer: 128 rows x 64 B, XOR-swizzled 16B granules:
//   granule q holds (row=q>>2, g=(q&3)^((q>>2)&3)); gather side inverts the
//   swizzle so global_load_lds's lane-linear dest constraint is satisfied.
__global__ __launch_bounds__(256, 4)
void gram_lse_kernel(const unsigned char* __restrict__ Mg,
                     float* __restrict__ rowsum, float* __restrict__ targets) {
    __shared__ __align__(16) char As[2][TILE * KB];   // 2 x 8 KB
    __shared__ __align__(16) char Bs[2][TILE * KB];   // 2 x 8 KB

    // XCD-banded order: dispatch d -> band d%8 (one XCD), 260 tiles per band.
    const int d = blockIdx.x;
    const int p = (d & 7) * 260 + (d >> 3);
    // triangular decode: p -> (bx, by) with by >= bx
    int by = (int)((sqrtf(8.0f * (float)p + 1.0f) - 1.0f) * 0.5f);
    while ((by + 1) * (by + 2) / 2 <= p) ++by;
    while (by * (by + 1) / 2 > p) --by;
    const int bx = p - by * (by + 1) / 2;

    const int rowBase = bx * TILE;
    const int colBase = by * TILE;
    const bool diag = (bx == by);
    const int tid  = threadIdx.x;
    const int wave = tid >> 6;
    const int lane = tid & 63;
    const int wr = (wave >> 1) * 64;
    const int wc = (wave & 1) * 64;
    const int l15 = lane & 15;
    const int l4  = lane >> 4;          // quad 0..3 (k-window selector)
    const int r3b = l15 & 3;
    const int qh = l4 >> 1, ql = l4 & 1;

    // staging gather (constant per thread): granule q=tid (+256/issue):
    //   dest row = tid>>2, dest gpos = tid&3, source g = gpos ^ (row&3).
    const int sg  = ((tid & 3) ^ ((tid >> 2) & 3)) * 16;
    const int sr  = tid >> 2;                        // 0..63 (+64 on issue 1)
    const unsigned char* gA = Mg + (size_t)(rowBase + sr) * DD + sg;
    const unsigned char* gB = Mg + (size_t)(colBase + sr) * DD + sg;
    const int ldst = tid * 16;                       // dest (+4096 on issue 1)

    // fragment read: row*64 + ((ks*2+qh) ^ (row&3))*16 + ql*8; row&3 == l15&3.
    const int so0 = (((0 + qh) ^ r3b) << 4) | (ql << 3);   // ks=0
    const int so1 = (((2 + qh) ^ r3b) << 4) | (ql << 3);   // ks=1
    const int arow = (wr + l15) * KB;
    const int brow = (wc + l15) * KB;

    f32x4 acc[4][4] = {};

    // prologue: stage chunk 0 into buffer 0
    #pragma unroll
    for (int i = 0; i < 2; ++i)
        gload_lds16(gA + (size_t)i * 64 * DD, &As[0][ldst + i * 4096]);
    if (!diag) {
        #pragma unroll
        for (int i = 0; i < 2; ++i)
            gload_lds16(gB + (size_t)i * 64 * DD, &Bs[0][ldst + i * 4096]);
    }
    __syncthreads();

    for (int c = 0; c < 8; ++c) {
        const int cur = c & 1, nxt = cur ^ 1;
        const char* Ab = As[cur];
        const char* Bb = diag ? As[cur] : Bs[cur];

        // 1) ds_reads for this chunk (before prefetch: no false vmcnt dep)
        long a0[4], a1[4], b0[4], b1[4];
        #pragma unroll
        for (int mi = 0; mi < 4; ++mi) {
            a0[mi] = *(const long*)(Ab + arow + mi * 1024 + so0);
            a1[mi] = *(const long*)(Ab + arow + mi * 1024 + so1);
        }
        #pragma unroll
        for (int ni = 0; ni < 4; ++ni) {
            b0[ni] = *(const long*)(Bb + brow + ni * 1024 + so0);
            b1[ni] = *(const long*)(Bb + brow + ni * 1024 + so1);
        }

        // 2) prefetch chunk c+1 into the other buffer (drains at the barrier,
        //    overlapped by the MFMAs below)
        if (c < 7) {
            const unsigned char* pA = gA + (c + 1) * KB;
            #pragma unroll
            for (int i = 0; i < 2; ++i)
                gload_lds16(pA + (size_t)i * 64 * DD, &As[nxt][ldst + i * 4096]);
            if (!diag) {
                const unsigned char* pB = gB + (c + 1) * KB;
                #pragma unroll
                for (int i = 0; i < 2; ++i)
                    gload_lds16(pB + (size_t)i * 64 * DD, &Bs[nxt][ldst + i * 4096]);
            }
        }

        // 3) MFMAs (k = ks*32 within the chunk)
        #pragma unroll
        for (int mi = 0; mi < 4; ++mi)
            #pragma unroll
            for (int ni = 0; ni < 4; ++ni) {
                acc[mi][ni] = __builtin_amdgcn_mfma_f32_16x16x32_fp8_fp8(
                    a0[mi], b0[ni], acc[mi][ni], 0, 0, 0);
                acc[mi][ni] = __builtin_amdgcn_mfma_f32_16x16x32_fp8_fp8(
                    a1[mi], b1[ni], acc[mi][ni], 0, 0, 0);
            }

        __syncthreads();   // drains prefetch (mostly complete) + buffer reuse
    }

    // ---- epilogue ----
    // C/D layout: col = lane&15, row = (lane>>4)*4 + reg  (dtype-independent)
    float cs[4] = {0.f, 0.f, 0.f, 0.f};   // column partials (off-diag tiles)
    #pragma unroll
    for (int mi = 0; mi < 4; ++mi) {
        float rs[4] = {0.f, 0.f, 0.f, 0.f};
        #pragma unroll
        for (int ni = 0; ni < 4; ++ni) {
            const int gcol = colBase + wc + ni * 16 + l15;
            #pragma unroll
            for (int r = 0; r < 4; ++r) {
                const int grow = rowBase + wr + mi * 16 + l4 * 4 + r;
                float logit = 10.f * acc[mi][ni][r];
                float e = __expf(logit - 10.f);
                if (grow == gcol) e = 0.f;     // exclude diagonal exactly
                rs[r] += e;
                cs[ni] += e;
                // targets: rows 0/1 of G give 10*G[t, j0] transposed.
                // Only bx==0 blocks write; disjoint col ranges -> plain store.
                if (rowBase == 0 && grow < 2) {
                    const int j0 = ((gcol & (BB - 1)) == 0) ? 1 : 0;
                    if (grow == j0) targets[gcol] = logit;
                }
            }
        }
        #pragma unroll
        for (int m = 1; m <= 8; m <<= 1)
            #pragma unroll
            for (int r = 0; r < 4; ++r)
                rs[r] += __shfl_xor(rs[r], m);
        if (l15 == 0) {
            #pragma unroll
            for (int r = 0; r < 4; ++r)
                atomicAdd(&rowsum[rowBase + wr + mi * 16 + l4 * 4 + r], rs[r]);
        }
    }
    if (!diag) {
        #pragma unroll
        for (int ni = 0; ni < 4; ++ni) {
            cs[ni] += __shfl_xor(cs[ni], 16);
            cs[ni] += __shfl_xor(cs[ni], 32);
        }
        if (l4 == 0) {
            #pragma unroll
            for (int ni = 0; ni < 4; ++ni)
                atomicAdd(&rowsum[colBase + wc + ni * 16 + l15], cs[ni]);
        }
    }
}

// ---------------- kernel 3: final scalar reduction -------------------------
__global__ __launch_bounds__(1024)
void finalize_kernel(const float* __restrict__ rowsum,
                     const float* __restrict__ targets, float* __restrict__ out) {
    const int tid = threadIdx.x;
    float s = 0.f;
    #pragma unroll
    for (int t = tid; t < NN; t += 1024)
        s += targets[t] - 10.f - __logf(rowsum[t]);
    #pragma unroll
    for (int off = 1; off <= 32; off <<= 1) s += __shfl_xor(s, off);
    __shared__ float red[16];
    if ((tid & 63) == 0) red[tid >> 6] = s;
    __syncthreads();
    if (tid == 0) {
        float t = 0.f;
        #pragma unroll
        for (int i = 0; i < 16; ++i) t += red[i];
        out[0] = -t / (float)NN;
    }
}

extern "C" void kernel_launch(void* const* d_in, const int* in_sizes, int n_in,
                              void* d_out, int out_size, void* d_ws, size_t ws_size,
                              hipStream_t stream) {
    const float* zi = (const float*)d_in[0];
    const float* zj = (const float*)d_in[1];

    unsigned char* M = (unsigned char*)d_ws;                         // 4 MB fp8
    float* rowsum  = (float*)((char*)d_ws + (size_t)NN * DD);        // 32 KB
    float* targets = rowsum + NN;                                    // 32 KB
    float* out = (float*)d_out;

    normalize_kernel<<<NN / 4, 256, 0, stream>>>(zi, zj, M, rowsum);
    gram_lse_kernel<<<NBLK, 256, 0, stream>>>(M, rowsum, targets);
    finalize_kernel<<<1, 1024, 0, stream>>>(rowsum, targets, out);
}